// Round 2
// baseline (259.048 us; speedup 1.0000x reference)
//
#include <hip/hip_runtime.h>
#include <hip/hip_bf16.h>

// ImmuneMemoryModule — fully-fused MI355X pipeline.
// prep: pack W1/W2/memory into kappa-permuted MFMA fragment layouts (bf16),
//       memory rows pre-normalized by 1/||m||; B_mat transposed to [10][512].
// mega: per wave = 16 rows end-to-end:
//       ff (fp32 VALU) -> GEMM2 (h in registers) -> GEMM3 (q in registers)
//       -> GEMM4 running max/argmax -> threshold -> gather/zero write.
// Key idea: MFMA contracts over lane-slots; relabeling k-slots consistently on
// both operands (kappa(g,j)) lets each lane keep its own row's h/q in VGPRs.

typedef __attribute__((ext_vector_type(8))) short short8;
typedef __attribute__((ext_vector_type(4))) float f32x4;

#define MFMA(a, b, c) __builtin_amdgcn_mfma_f32_16x16x32_bf16((a), (b), (c), 0, 0, 0)

static __device__ __forceinline__ short bfb(float f) {
  return (short)__builtin_bit_cast(unsigned short, __float2bfloat16(f));
}

typedef const __attribute__((address_space(1))) unsigned int* gas_p;
typedef __attribute__((address_space(3))) unsigned int* las_p;
static __device__ __forceinline__ void async16(const void* g, void* l) {
  __builtin_amdgcn_global_load_lds((gas_p)g, (las_p)l, 16, 0, 0);
}

// ---------------------------------------------------------------------------
// prep
// Mp  [16 chunks][4 nt][8 kt][16 jj][4 g][8 j]  bf16, rows pre-scaled 1/|m|
//     kappa4 = 32*kt + (j>>2)*16 + 4*g + (j&3)
// W2p [16 kt][16 ct3][16 jj][4 g][8 j]          kappa3 same formula
// W1p [32 ct][16 jj][4 g][8 j]                  kappa2 = 4*j+g (j<5), else 0
// Bt  [10][512] f32
// ---------------------------------------------------------------------------
__global__ __launch_bounds__(256) void prep_kernel(
    const float* __restrict__ Bmat, const float* __restrict__ W1,
    const float* __restrict__ W2, const float* __restrict__ mem,
    float* __restrict__ Bt, __hip_bfloat16* __restrict__ W1p,
    __hip_bfloat16* __restrict__ W2p, __hip_bfloat16* __restrict__ Mp) {
  const int b = blockIdx.x, tid = threadIdx.x;
  if (b < 16) {
    __shared__ float invl[64];
    const int w = tid >> 6, lane = tid & 63, g = lane >> 4, jj = lane & 15;
    {
      int r = w * 16 + jj;  // 0..63
      const float4* m4 = (const float4*)(mem + (size_t)(b * 64 + r) * 256);
      float ss = 0.f;
      for (int t = 0; t < 16; ++t) {
        float4 v = m4[g * 16 + t];
        ss += v.x * v.x + v.y * v.y + v.z * v.z + v.w * v.w;
      }
      ss += __shfl_xor(ss, 16);
      ss += __shfl_xor(ss, 32);
      if (g == 0) invl[r] = rsqrtf(fmaxf(ss, 1e-30f));
    }
    __syncthreads();
    for (int u = 0; u < 64; ++u) {
      int idx = u * 256 + tid;  // 0..16383
      int j = idx & 7, g2 = (idx >> 3) & 3, jp = (idx >> 5) & 15;
      int kt = (idx >> 9) & 7, ntl = idx >> 12;
      int kap = 32 * kt + (j >> 2) * 16 + 4 * g2 + (j & 3);
      int row = ntl * 16 + jp;
      float v = mem[(size_t)(b * 64 + row) * 256 + kap] * invl[row];
      Mp[(size_t)b * 16384 + idx] = __float2bfloat16(v);
    }
  } else if (b == 16) {
    for (int idx = tid; idx < 16384; idx += 256) {
      int j = idx & 7, g2 = (idx >> 3) & 3, jp = (idx >> 5) & 15, ct = idx >> 9;
      float v = 0.f;
      if (j < 5) v = W1[(4 * j + g2) * 512 + ct * 16 + jp];
      W1p[idx] = __float2bfloat16(v);
    }
  } else if (b == 33) {
    for (int idx = tid; idx < 5120; idx += 256) {
      int f = idx >> 9, d = idx & 511;
      Bt[idx] = Bmat[d * 10 + f];
    }
  } else {  // b = 17..32 -> W2p
    int bb = b - 17;
    for (int u = 0; u < 32; ++u) {
      int idx = bb * 8192 + u * 256 + tid;  // 0..131071
      int j = idx & 7, g2 = (idx >> 3) & 3, jp = (idx >> 5) & 15;
      int ct3 = (idx >> 9) & 15, kt = idx >> 13;
      int kap = 32 * kt + (j >> 2) * 16 + 4 * g2 + (j & 3);
      W2p[idx] = __float2bfloat16(W2[(size_t)kap * 256 + ct3 * 16 + jp]);
    }
  }
}

// ---------------------------------------------------------------------------
// mega: 256 threads, 4 waves, 64 rows/block (16 rows/wave), grid 1024.
// ---------------------------------------------------------------------------
__global__ __launch_bounds__(256) void mega_kernel(
    const float* __restrict__ query, const float* __restrict__ Bt,
    const __hip_bfloat16* __restrict__ W1p, const float* __restrict__ b1,
    const __hip_bfloat16* __restrict__ W2p, const float* __restrict__ b2,
    const __hip_bfloat16* __restrict__ Mp, const float* __restrict__ mem,
    float* __restrict__ out) {
  __shared__ __align__(16) char lds[32768];
  const int tid = threadIdx.x, w = tid >> 6, lane = tid & 63;
  const int g = lane >> 4, jj = lane & 15;
  const int rowBase = blockIdx.x * 64 + w * 16;
  const f32x4 z4 = {0.f, 0.f, 0.f, 0.f};

  // ---- FF: xp = query_row . B_mat (fp32 exact), per-lane k-range [g*128,+128)
  float xa[10];
#pragma unroll
  for (int f = 0; f < 10; ++f) xa[f] = 0.f;
  {
    const float4* q4 = (const float4*)query + (size_t)(rowBase + jj) * 128 + g * 32;
    const float4* bt4 = (const float4*)Bt + g * 32;
#pragma unroll 4
    for (int i = 0; i < 32; ++i) {
      float4 qv = q4[i];
#pragma unroll
      for (int f = 0; f < 10; ++f) {
        float4 bv = bt4[f * 128 + i];
        xa[f] = fmaf(qv.x, bv.x, fmaf(qv.y, bv.y, fmaf(qv.z, bv.z, fmaf(qv.w, bv.w, xa[f]))));
      }
    }
#pragma unroll
    for (int f = 0; f < 10; ++f) {
      xa[f] += __shfl_xor(xa[f], 16);
      xa[f] += __shfl_xor(xa[f], 32);
    }
  }
  // ff B-frag: slot (g,j) holds k = 4j+g (j<5): k<10 -> sin(xp[k]), else cos(xp[k-10])
  short8 ffb;
  {
    const bool gl = g & 1, gh = g & 2;
    float s0 = gh ? (gl ? xa[3] : xa[2]) : (gl ? xa[1] : xa[0]);  // k=g      -> sin
    float s1 = gh ? (gl ? xa[7] : xa[6]) : (gl ? xa[5] : xa[4]);  // k=4+g    -> sin
    float s2 = gh ? (gl ? xa[1] : xa[0]) : (gl ? xa[9] : xa[8]);  // k=8+g
    float s3 = gh ? (gl ? xa[5] : xa[4]) : (gl ? xa[3] : xa[2]);  // k=12+g   -> cos
    float s4 = gh ? (gl ? xa[9] : xa[8]) : (gl ? xa[7] : xa[6]);  // k=16+g   -> cos
    float v2 = (g < 2) ? sinf(s2) : cosf(s2);
    ffb[0] = bfb(sinf(s0));
    ffb[1] = bfb(sinf(s1));
    ffb[2] = bfb(v2);
    ffb[3] = bfb(cosf(s3));
    ffb[4] = bfb(cosf(s4));
    ffb[5] = 0; ffb[6] = 0; ffb[7] = 0;
  }

  // ---- GEMM2: h = relu(ff@W1+b1); lane holds h[row jj][16ct+4g+reg] -> hfrag
  short8 hfrag[16];
  {
    const short8* w1f = (const short8*)W1p;
#pragma unroll
    for (int ct = 0; ct < 32; ++ct) {
      short8 a = w1f[(ct * 16 + jj) * 4 + g];
      f32x4 bb = *(const f32x4*)(b1 + ct * 16 + 4 * g);
      f32x4 d = MFMA(a, ffb, z4);
#pragma unroll
      for (int i = 0; i < 4; ++i) {
        float v = d[i] + bb[i];
        v = v > 0.f ? v : 0.f;
        hfrag[ct >> 1][(ct & 1) * 4 + i] = bfb(v);
      }
    }
  }

  // ---- GEMM3: q = h@W2+b2, W2p streamed through LDS (8 stages x 32KB)
  f32x4 acc3[16];
#pragma unroll
  for (int c = 0; c < 16; ++c) acc3[c] = z4;
  {
    const char* w2g = (const char*)W2p;
#pragma unroll
    for (int s = 0; s < 8; ++s) {
      __syncthreads();
#pragma unroll
      for (int i = 0; i < 8; ++i)
        async16(w2g + s * 32768 + (i * 256 + tid) * 16, lds + (i * 256 + tid) * 16);
      __syncthreads();
#pragma unroll
      for (int ktl = 0; ktl < 2; ++ktl) {
        const int kt = s * 2 + ktl;
#pragma unroll
        for (int c = 0; c < 16; ++c) {
          short8 a = *(const short8*)(lds + (ktl * 256 + c * 16 + jj) * 64 + g * 16);
          acc3[c] = MFMA(a, hfrag[kt], acc3[c]);
        }
      }
    }
  }
  // epilogue: bias, |q|^2, pack q bf16 (raw; 1/|q| applied to final max only)
  short8 qfrag[8];
  float qn = 0.f;
#pragma unroll
  for (int c = 0; c < 16; ++c) {
    f32x4 bb = *(const f32x4*)(b2 + c * 16 + 4 * g);
#pragma unroll
    for (int i = 0; i < 4; ++i) {
      float v = acc3[c][i] + bb[i];
      qn += v * v;
      qfrag[c >> 1][(c & 1) * 4 + i] = bfb(v);
    }
  }
  qn += __shfl_xor(qn, 16);
  qn += __shfl_xor(qn, 32);
  const float invqn = rsqrtf(fmaxf(qn, 1e-30f));

  // ---- GEMM4: running max/argmax of q . m_n/|m_n| ; Mp streamed (16 x 32KB)
  float runmax[4];
  int runidx[4];
#pragma unroll
  for (int i = 0; i < 4; ++i) { runmax[i] = -1e30f; runidx[i] = 0; }
  {
    const char* mpg = (const char*)Mp;
    for (int cch = 0; cch < 16; ++cch) {
      __syncthreads();
#pragma unroll
      for (int i = 0; i < 8; ++i)
        async16(mpg + cch * 32768 + (i * 256 + tid) * 16, lds + (i * 256 + tid) * 16);
      __syncthreads();
      f32x4 a4[4];
#pragma unroll
      for (int nl = 0; nl < 4; ++nl) a4[nl] = z4;
#pragma unroll
      for (int kt = 0; kt < 8; ++kt) {
#pragma unroll
        for (int nl = 0; nl < 4; ++nl) {
          short8 bfr = *(const short8*)(lds + ((nl * 8 + kt) * 16 + jj) * 64 + g * 16);
          a4[nl] = MFMA(qfrag[kt], bfr, a4[nl]);
        }
      }
#pragma unroll
      for (int nl = 0; nl < 4; ++nl) {
        int n = (cch * 4 + nl) * 16 + jj;
#pragma unroll
        for (int i = 0; i < 4; ++i) {
          if (a4[nl][i] > runmax[i]) { runmax[i] = a4[nl][i]; runidx[i] = n; }
        }
      }
    }
  }

  // ---- reduce across jj-lanes (first-max tie-break), threshold, write
#pragma unroll
  for (int i = 0; i < 4; ++i) {
#pragma unroll
    for (int o = 1; o < 16; o <<= 1) {
      float v2 = __shfl_xor(runmax[i], o);
      int i2 = __shfl_xor(runidx[i], o);
      if (v2 > runmax[i] || (v2 == runmax[i] && i2 < runidx[i])) {
        runmax[i] = v2;
        runidx[i] = i2;
      }
    }
  }
  const float4* mem4 = (const float4*)mem;
  float4* out4 = (float4*)out;
#pragma unroll
  for (int i = 0; i < 4; ++i) {
    float iq = __shfl(invqn, 4 * g + i, 64);  // lane with jj == 4g+i
    float ms = runmax[i] * iq;
    int s = (ms < 0.7f) ? -1 : runidx[i];
    size_t row = (size_t)rowBase + 4 * g + i;
#pragma unroll
    for (int cq = 0; cq < 4; ++cq) {
      int col = cq * 16 + jj;
      float4 v = {0.f, 0.f, 0.f, 0.f};
      if (s >= 0) v = mem4[(size_t)s * 64 + col];
      out4[row * 64 + col] = v;
    }
  }
}

extern "C" void kernel_launch(void* const* d_in, const int* in_sizes, int n_in,
                              void* d_out, int out_size, void* d_ws, size_t ws_size,
                              hipStream_t stream) {
  const float* query = (const float*)d_in[0];
  const float* Bmat = (const float*)d_in[1];
  const float* W1 = (const float*)d_in[2];
  const float* b1 = (const float*)d_in[3];
  const float* W2 = (const float*)d_in[4];
  const float* b2 = (const float*)d_in[5];
  const float* mem = (const float*)d_in[6];
  float* out = (float*)d_out;

  char* ws = (char*)d_ws;
  __hip_bfloat16* Mp = (__hip_bfloat16*)ws;              // 512 KB
  __hip_bfloat16* W2p = (__hip_bfloat16*)(ws + 524288);  // 256 KB
  __hip_bfloat16* W1p = (__hip_bfloat16*)(ws + 786432);  // 32 KB
  float* Bt = (float*)(ws + 819200);                     // 20 KB

  prep_kernel<<<dim3(34), dim3(256), 0, stream>>>(Bmat, W1, W2, mem, Bt, W1p, W2p, Mp);
  mega_kernel<<<dim3(1024), dim3(256), 0, stream>>>(query, Bt, W1p, b1, W2p, b2, Mp, mem, out);
}

// Round 3
// 224.691 us; speedup vs baseline: 1.1529x; 1.1529x over previous
//
#include <hip/hip_runtime.h>
#include <hip/hip_bf16.h>

// ImmuneMemoryModule — fused MI355X pipeline, no-LDS operand path.
// prep: pack W1/W2/memory into kappa-permuted, LANE-CONTIGUOUS fragment
//       layouts ([frag][lane 0..63][8 bf16] = 1KB per wave-fragment), memory
//       rows pre-scaled by 1/||m||; B_mat transposed to [10][512].
// mega: per wave = 16 rows end-to-end, zero LDS, zero barriers:
//       ff (fp32 VALU) -> {GEMM2 h-slice + GEMM3 accumulate} per kt
//       -> qfrag -> GEMM4 running max/argmax -> threshold -> gather/zero.
// Operands (768KB total) are L2/L3-resident broadcasts: direct global short8
// loads of contiguous 1KB wave-fragments (coalesced, L1-friendly), per
// Common-mistake #7 (don't LDS-stage cache-resident data).

typedef __attribute__((ext_vector_type(8))) short short8;
typedef __attribute__((ext_vector_type(4))) float f32x4;

#define MFMA(a, b, c) __builtin_amdgcn_mfma_f32_16x16x32_bf16((a), (b), (c), 0, 0, 0)

static __device__ __forceinline__ short bfb(float f) {
  return (short)__builtin_bit_cast(unsigned short, __float2bfloat16(f));
}

// ---------------------------------------------------------------------------
// prep
// kappa(kt,g,j) = 32*kt + 16*(j>>2) + 4*g + (j&3)   (k-slot relabeling)
// W1p [32 ct][64 lane][8 j]   = W1[4j+g][ct*16+jj]          (j<5, else 0)
// W2p [16 kt][16 c][64 lane][8 j] = W2[kappa][c*16+jj]
// Mp  [16 cch][4 nl][8 kt][64 lane][8 j] = mhat[(cch*4+nl)*16+jj][kappa]
// Bt  [10][512] f32
// ---------------------------------------------------------------------------
__global__ __launch_bounds__(256) void prep_kernel(
    const float* __restrict__ Bmat, const float* __restrict__ W1,
    const float* __restrict__ W2, const float* __restrict__ mem,
    float* __restrict__ Bt, __hip_bfloat16* __restrict__ W1p,
    __hip_bfloat16* __restrict__ W2p, __hip_bfloat16* __restrict__ Mp) {
  const int b = blockIdx.x, tid = threadIdx.x;
  if (b < 16) {
    __shared__ float invl[64];
    const int w = tid >> 6, lane = tid & 63, g = lane >> 4, jj = lane & 15;
    {
      int r = w * 16 + jj;  // 0..63 local row
      const float4* m4 = (const float4*)(mem + (size_t)(b * 64 + r) * 256);
      float ss = 0.f;
      for (int t = 0; t < 16; ++t) {
        float4 v = m4[g * 16 + t];
        ss += v.x * v.x + v.y * v.y + v.z * v.z + v.w * v.w;
      }
      ss += __shfl_xor(ss, 16);
      ss += __shfl_xor(ss, 32);
      if (g == 0) invl[r] = rsqrtf(fmaxf(ss, 1e-30f));
    }
    __syncthreads();
    for (int u = 0; u < 64; ++u) {
      int t = u * 256 + tid;  // 0..16383 within this chunk
      int j = t & 7, lane2 = (t >> 3) & 63, kt = (t >> 9) & 7, nl = t >> 12;
      int g2 = lane2 >> 4, jp = lane2 & 15;
      int nloc = nl * 16 + jp;
      int kap = 32 * kt + 16 * (j >> 2) + 4 * g2 + (j & 3);
      float v = mem[(size_t)(b * 64 + nloc) * 256 + kap] * invl[nloc];
      Mp[(size_t)b * 16384 + t] = __float2bfloat16(v);
    }
  } else if (b == 16) {
    for (int idx = tid; idx < 16384; idx += 256) {
      int j = idx & 7, lane2 = (idx >> 3) & 63, ct = idx >> 9;
      int g2 = lane2 >> 4, jp = lane2 & 15;
      float v = 0.f;
      if (j < 5) v = W1[(4 * j + g2) * 512 + ct * 16 + jp];
      W1p[idx] = __float2bfloat16(v);
    }
  } else if (b == 33) {
    for (int idx = tid; idx < 5120; idx += 256) {
      int f = idx >> 9, d = idx & 511;
      Bt[idx] = Bmat[d * 10 + f];
    }
  } else {  // b = 17..32 -> W2p (131072 elems)
    int bb = b - 17;
    for (int u = 0; u < 32; ++u) {
      int idx = bb * 8192 + u * 256 + tid;
      int j = idx & 7, lane2 = (idx >> 3) & 63, c = (idx >> 9) & 15, kt = idx >> 13;
      int g2 = lane2 >> 4, jp = lane2 & 15;
      int kap = 32 * kt + 16 * (j >> 2) + 4 * g2 + (j & 3);
      W2p[idx] = __float2bfloat16(W2[(size_t)kap * 256 + c * 16 + jp]);
    }
  }
}

// ---------------------------------------------------------------------------
// mega: 256 threads (4 independent waves), 16 rows/wave, grid 1024. No LDS.
// ---------------------------------------------------------------------------
__global__ __launch_bounds__(256, 3) void mega_kernel(
    const float* __restrict__ query, const float* __restrict__ Bt,
    const __hip_bfloat16* __restrict__ W1p, const float* __restrict__ b1,
    const __hip_bfloat16* __restrict__ W2p, const float* __restrict__ b2,
    const __hip_bfloat16* __restrict__ Mp, const float* __restrict__ mem,
    float* __restrict__ out) {
  const int tid = threadIdx.x, w = tid >> 6, lane = tid & 63;
  const int g = lane >> 4, jj = lane & 15;
  const int rowBase = blockIdx.x * 64 + w * 16;
  const f32x4 z4 = {0.f, 0.f, 0.f, 0.f};

  // ---- FF: xp = query_row . B_mat (fp32), per-lane k-range [g*128, +128)
  float xa[10];
#pragma unroll
  for (int f = 0; f < 10; ++f) xa[f] = 0.f;
  {
    const float4* q4 = (const float4*)query + (size_t)(rowBase + jj) * 128 + g * 32;
    const float4* bt4 = (const float4*)Bt + g * 32;
#pragma unroll 4
    for (int i = 0; i < 32; ++i) {
      float4 qv = q4[i];
#pragma unroll
      for (int f = 0; f < 10; ++f) {
        float4 bv = bt4[f * 128 + i];
        xa[f] = fmaf(qv.x, bv.x, fmaf(qv.y, bv.y, fmaf(qv.z, bv.z, fmaf(qv.w, bv.w, xa[f]))));
      }
    }
#pragma unroll
    for (int f = 0; f < 10; ++f) {
      xa[f] += __shfl_xor(xa[f], 16);
      xa[f] += __shfl_xor(xa[f], 32);
    }
  }
  // ff B-frag: slot (g,j) holds k = 4j+g (j<5): k<10 -> sin(xp[k]), else cos(xp[k-10])
  short8 ffb;
  {
    const bool gl = g & 1, gh = g & 2;
    float s0 = gh ? (gl ? xa[3] : xa[2]) : (gl ? xa[1] : xa[0]);
    float s1 = gh ? (gl ? xa[7] : xa[6]) : (gl ? xa[5] : xa[4]);
    float s2 = gh ? (gl ? xa[1] : xa[0]) : (gl ? xa[9] : xa[8]);
    float s3 = gh ? (gl ? xa[5] : xa[4]) : (gl ? xa[3] : xa[2]);
    float s4 = gh ? (gl ? xa[9] : xa[8]) : (gl ? xa[7] : xa[6]);
    float v2 = (g < 2) ? sinf(s2) : cosf(s2);
    ffb[0] = bfb(sinf(s0));
    ffb[1] = bfb(sinf(s1));
    ffb[2] = bfb(v2);
    ffb[3] = bfb(cosf(s3));
    ffb[4] = bfb(cosf(s4));
    ffb[5] = 0; ffb[6] = 0; ffb[7] = 0;
  }

  // ---- GEMM2+3 fused over kt: h-slice (1 short8) -> immediately consumed
  const short8* w1f = (const short8*)W1p;
  const short8* w2f = (const short8*)W2p;
  f32x4 acc3[16];
#pragma unroll
  for (int c = 0; c < 16; ++c) acc3[c] = z4;

  for (int kt = 0; kt < 16; ++kt) {
    short8 hf;
#pragma unroll
    for (int half = 0; half < 2; ++half) {
      const int ct = kt * 2 + half;
      short8 a = w1f[ct * 64 + lane];
      f32x4 bb = *(const f32x4*)(b1 + ct * 16 + 4 * g);
      f32x4 d = MFMA(a, ffb, z4);
#pragma unroll
      for (int i = 0; i < 4; ++i) {
        float v = d[i] + bb[i];
        v = v > 0.f ? v : 0.f;
        hf[half * 4 + i] = bfb(v);
      }
    }
    const short8* w2k = w2f + (size_t)kt * 1024;  // 16 c * 64 lanes
#pragma unroll
    for (int c = 0; c < 16; ++c)
      acc3[c] = MFMA(w2k[c * 64 + lane], hf, acc3[c]);
  }

  // epilogue: bias, |q|^2, pack q bf16 (1/|q| applied to the final max only)
  short8 qfrag[8];
  float qn = 0.f;
#pragma unroll
  for (int c = 0; c < 16; ++c) {
    f32x4 bb = *(const f32x4*)(b2 + c * 16 + 4 * g);
#pragma unroll
    for (int i = 0; i < 4; ++i) {
      float v = acc3[c][i] + bb[i];
      qn += v * v;
      qfrag[c >> 1][(c & 1) * 4 + i] = bfb(v);
    }
  }
  qn += __shfl_xor(qn, 16);
  qn += __shfl_xor(qn, 32);
  const float invqn = rsqrtf(fmaxf(qn, 1e-30f));

  // ---- GEMM4: running max/argmax of q . m_n/|m_n| (direct global frags)
  float runmax[4];
  int runidx[4];
#pragma unroll
  for (int i = 0; i < 4; ++i) { runmax[i] = -1e30f; runidx[i] = 0; }
  const short8* mp8 = (const short8*)Mp;

  for (int cch = 0; cch < 16; ++cch) {
    const short8* mpc = mp8 + (size_t)cch * 2048;  // 4 nl * 8 kt * 64 lanes
    f32x4 a4[4];
#pragma unroll
    for (int nl = 0; nl < 4; ++nl) a4[nl] = z4;
#pragma unroll
    for (int kt = 0; kt < 8; ++kt)
#pragma unroll
      for (int nl = 0; nl < 4; ++nl)
        a4[nl] = MFMA(qfrag[kt], mpc[(nl * 8 + kt) * 64 + lane], a4[nl]);
#pragma unroll
    for (int nl = 0; nl < 4; ++nl) {
      int n = (cch * 4 + nl) * 16 + jj;
#pragma unroll
      for (int i = 0; i < 4; ++i) {
        if (a4[nl][i] > runmax[i]) { runmax[i] = a4[nl][i]; runidx[i] = n; }
      }
    }
  }

  // ---- reduce across jj-lanes (first-max tie-break), threshold, write
#pragma unroll
  for (int i = 0; i < 4; ++i) {
#pragma unroll
    for (int o = 1; o < 16; o <<= 1) {
      float v2 = __shfl_xor(runmax[i], o);
      int i2 = __shfl_xor(runidx[i], o);
      if (v2 > runmax[i] || (v2 == runmax[i] && i2 < runidx[i])) {
        runmax[i] = v2;
        runidx[i] = i2;
      }
    }
  }
  const float4* mem4 = (const float4*)mem;
  float4* out4 = (float4*)out;
#pragma unroll
  for (int i = 0; i < 4; ++i) {
    float iq = __shfl(invqn, 4 * g + i, 64);  // lane with jj == 4g+i
    float ms = runmax[i] * iq;
    int s = (ms < 0.7f) ? -1 : runidx[i];
    size_t row = (size_t)rowBase + 4 * g + i;
#pragma unroll
    for (int cq = 0; cq < 4; ++cq) {
      int col = cq * 16 + jj;
      float4 v = {0.f, 0.f, 0.f, 0.f};
      if (s >= 0) v = mem4[(size_t)s * 64 + col];
      out4[row * 64 + col] = v;
    }
  }
}

extern "C" void kernel_launch(void* const* d_in, const int* in_sizes, int n_in,
                              void* d_out, int out_size, void* d_ws, size_t ws_size,
                              hipStream_t stream) {
  const float* query = (const float*)d_in[0];
  const float* Bmat = (const float*)d_in[1];
  const float* W1 = (const float*)d_in[2];
  const float* b1 = (const float*)d_in[3];
  const float* W2 = (const float*)d_in[4];
  const float* b2 = (const float*)d_in[5];
  const float* mem = (const float*)d_in[6];
  float* out = (float*)d_out;

  char* ws = (char*)d_ws;
  __hip_bfloat16* Mp = (__hip_bfloat16*)ws;              // 512 KB
  __hip_bfloat16* W2p = (__hip_bfloat16*)(ws + 524288);  // 256 KB
  __hip_bfloat16* W1p = (__hip_bfloat16*)(ws + 786432);  // 32 KB
  float* Bt = (float*)(ws + 819200);                     // 20 KB

  prep_kernel<<<dim3(34), dim3(256), 0, stream>>>(Bmat, W1, W2, mem, Bt, W1p, W2p, Mp);
  mega_kernel<<<dim3(1024), dim3(256), 0, stream>>>(query, Bt, W1p, b1, W2p, b2, Mp, mem, out);
}

// Round 4
// 117.176 us; speedup vs baseline: 2.2108x; 1.9175x over previous
//
#include <hip/hip_runtime.h>
#include <hip/hip_bf16.h>

// ImmuneMemoryModule — MI355X pipeline v4.
// prep: pack W1/W2/memory into kappa-permuted lane-contiguous fragment layouts
//       (bf16); memory rows pre-scaled by 1/||m||.
// ff:   xp = query @ B_mat (fp32, coalesced, memory-bound) -> ff [B][32] bf16
//       (linear k: k<10 sin, 10..19 cos, >=20 zero) = A-frag-ready layout.
// mega: 8 waves/block, 256 rows/block, grid 256 (1 block/CU, all resident).
//       Operand slabs (W2p 16KB, Mp 32KB) double-buffered in LDS via
//       global_load_lds; all 8 waves share them through conflict-free
//       ds_read_b128 (lane-contiguous 1KB fragments). h/q stay in registers
//       (kappa slot-relabeling). One barrier per slab.

typedef __attribute__((ext_vector_type(8))) short short8;
typedef __attribute__((ext_vector_type(4))) float f32x4;

#define MFMA(a, b, c) __builtin_amdgcn_mfma_f32_16x16x32_bf16((a), (b), (c), 0, 0, 0)

static __device__ __forceinline__ short bfb(float f) {
  return (short)__builtin_bit_cast(unsigned short, __float2bfloat16(f));
}
static __device__ __forceinline__ unsigned short bf16bits(float f) {
  return __builtin_bit_cast(unsigned short, __float2bfloat16(f));
}
static __device__ __forceinline__ float sel10(const float a[10], int i) {
  float v = a[0];
#pragma unroll
  for (int j = 1; j < 10; ++j) v = (i == j) ? a[j] : v;
  return v;
}

typedef const __attribute__((address_space(1))) unsigned int* gas_p;
typedef __attribute__((address_space(3))) unsigned int* las_p;
static __device__ __forceinline__ void async16(const void* g, void* l) {
  __builtin_amdgcn_global_load_lds((gas_p)g, (las_p)l, 16, 0, 0);
}

// ---------------------------------------------------------------------------
// prep
// kappa(kt,g,j) = 32*kt + 16*(j>>2) + 4*g + (j&3)
// W1p [32 ct][64 lane][8 j]       = W1[8g+j][ct*16+jj]       (8g+j<20 else 0)
// W2p [16 kt][16 c][64 lane][8 j] = W2[kappa][c*16+jj]
// Mp  [16 cch][4 nl][8 kt][64 lane][8 j] = mhat[(cch*4+nl)*16+jj][kappa]
// ---------------------------------------------------------------------------
__global__ __launch_bounds__(256) void prep_kernel(
    const float* __restrict__ W1, const float* __restrict__ W2,
    const float* __restrict__ mem, __hip_bfloat16* __restrict__ W1p,
    __hip_bfloat16* __restrict__ W2p, __hip_bfloat16* __restrict__ Mp) {
  const int b = blockIdx.x, tid = threadIdx.x;
  if (b < 16) {
    __shared__ float invl[64];
    const int w = tid >> 6, lane = tid & 63, g = lane >> 4, jj = lane & 15;
    {
      int r = w * 16 + jj;  // 0..63 local row
      const float4* m4 = (const float4*)(mem + (size_t)(b * 64 + r) * 256);
      float ss = 0.f;
      for (int t = 0; t < 16; ++t) {
        float4 v = m4[g * 16 + t];
        ss += v.x * v.x + v.y * v.y + v.z * v.z + v.w * v.w;
      }
      ss += __shfl_xor(ss, 16);
      ss += __shfl_xor(ss, 32);
      if (g == 0) invl[r] = rsqrtf(fmaxf(ss, 1e-30f));
    }
    __syncthreads();
    for (int u = 0; u < 64; ++u) {
      int t = u * 256 + tid;  // 0..16383 within this chunk
      int j = t & 7, lane2 = (t >> 3) & 63, kt = (t >> 9) & 7, nl = t >> 12;
      int g2 = lane2 >> 4, jp = lane2 & 15;
      int nloc = nl * 16 + jp;
      int kap = 32 * kt + 16 * (j >> 2) + 4 * g2 + (j & 3);
      float v = mem[(size_t)(b * 64 + nloc) * 256 + kap] * invl[nloc];
      Mp[(size_t)b * 16384 + t] = __float2bfloat16(v);
    }
  } else if (b == 16) {
    for (int idx = tid; idx < 16384; idx += 256) {
      int j = idx & 7, lane2 = (idx >> 3) & 63, ct = idx >> 9;
      int g2 = lane2 >> 4, jp = lane2 & 15;
      int k = 8 * g2 + j;
      float v = (k < 20) ? W1[k * 512 + ct * 16 + jp] : 0.f;
      W1p[idx] = __float2bfloat16(v);
    }
  } else {  // b = 17..32 -> W2p (131072 elems)
    int bb = b - 17;
    for (int u = 0; u < 32; ++u) {
      int idx = bb * 8192 + u * 256 + tid;
      int j = idx & 7, lane2 = (idx >> 3) & 63, c = (idx >> 9) & 15, kt = idx >> 13;
      int g2 = lane2 >> 4, jp = lane2 & 15;
      int kap = 32 * kt + 16 * (j >> 2) + 4 * g2 + (j & 3);
      W2p[idx] = __float2bfloat16(W2[(size_t)kap * 256 + c * 16 + jp]);
    }
  }
}

// ---------------------------------------------------------------------------
// ff: 16-lane group per row, coalesced float4 loads, LDS-staged B_mat.
// ff output [B][32] bf16 linear: k<10 sin(xp[k]), 10..19 cos(xp[k-10]), else 0.
// ---------------------------------------------------------------------------
__global__ __launch_bounds__(256) void ff_kernel(
    const float* __restrict__ query, const float* __restrict__ Bmat,
    __hip_bfloat16* __restrict__ ff) {
  __shared__ __align__(16) float Bl[10 * 512];  // [f][d], 20 KB
  for (int i = threadIdx.x; i < 5120; i += 256) {
    int d = i / 10, f = i - d * 10;
    Bl[f * 512 + d] = Bmat[i];  // B_mat row-major [512][10]
  }
  __syncthreads();
  const int wv = threadIdx.x >> 6, lane = threadIdx.x & 63;
  const int g = lane >> 4, jj = lane & 15;
  const long row = (long)blockIdx.x * 16 + wv * 4 + g;
  const float4* q4 = (const float4*)(query + row * 512);

  float acc[10];
#pragma unroll
  for (int f = 0; f < 10; ++f) acc[f] = 0.f;
#pragma unroll
  for (int k = 0; k < 8; ++k) {
    float4 qv = q4[jj + 16 * k];
#pragma unroll
    for (int f = 0; f < 10; ++f) {
      float4 bv = *(const float4*)(Bl + f * 512 + 4 * (jj + 16 * k));
      acc[f] = fmaf(qv.x, bv.x, fmaf(qv.y, bv.y, fmaf(qv.z, bv.z, fmaf(qv.w, bv.w, acc[f]))));
    }
  }
#pragma unroll
  for (int f = 0; f < 10; ++f) {
    float s = acc[f];
    s += __shfl_xor(s, 1); s += __shfl_xor(s, 2);
    s += __shfl_xor(s, 4); s += __shfl_xor(s, 8);
    acc[f] = s;
  }
  // lane jj writes bf16 pair for k = 2jj, 2jj+1
  int base = (jj < 5) ? 2 * jj : 2 * jj - 10;
  float a0 = sel10(acc, base);
  float a1 = sel10(acc, base + 1);
  float v0 = 0.f, v1 = 0.f;
  if (jj < 5) { v0 = sinf(a0); v1 = sinf(a1); }
  else if (jj < 10) { v0 = cosf(a0); v1 = cosf(a1); }
  ushort2 pk;
  pk.x = bf16bits(v0);
  pk.y = bf16bits(v1);
  ((ushort2*)ff)[row * 16 + jj] = pk;
}

// ---------------------------------------------------------------------------
// mega: 512 threads (8 waves), 32 rows/wave (2 row-tiles), grid 256.
// LDS: [0,32K) W2 double-buffer (2x16K), [32K,96K) Mp double-buffer (2x32K).
// ---------------------------------------------------------------------------
#define STAGE_W2(slab, bufi)                                             \
  do {                                                                   \
    const char* s_ = (const char*)W2p + (slab)*16384 + tid * 16;         \
    char* d_ = lds + (bufi)*16384 + tid * 16;                            \
    async16(s_, d_);                                                     \
    async16(s_ + 8192, d_ + 8192);                                       \
  } while (0)

#define STAGE_MP(slab, bufi)                                             \
  do {                                                                   \
    const char* s_ = (const char*)Mp + (slab)*32768 + tid * 16;          \
    char* d_ = lds + 32768 + (bufi)*32768 + tid * 16;                    \
    async16(s_, d_);                                                     \
    async16(s_ + 8192, d_ + 8192);                                       \
    async16(s_ + 16384, d_ + 16384);                                     \
    async16(s_ + 24576, d_ + 24576);                                     \
  } while (0)

__global__ __launch_bounds__(512, 2) void mega_kernel(
    const __hip_bfloat16* __restrict__ ff, const __hip_bfloat16* __restrict__ W1p,
    const float* __restrict__ b1, const __hip_bfloat16* __restrict__ W2p,
    const float* __restrict__ b2, const __hip_bfloat16* __restrict__ Mp,
    const float* __restrict__ mem, float* __restrict__ out) {
  __shared__ __align__(16) char lds[98304];
  const int tid = threadIdx.x, w = tid >> 6, lane = tid & 63;
  const int g = lane >> 4, jj = lane & 15;
  const int rowBase = blockIdx.x * 256 + w * 32;
  const f32x4 z4 = {0.f, 0.f, 0.f, 0.f};
  const short8* w1f = (const short8*)W1p;

  STAGE_W2(0, 0);

  // ff A-frags (linear layout: slot (g,j) = ff[row][8g+j])
  short8 ffq[2];
#pragma unroll
  for (int rt = 0; rt < 2; ++rt)
    ffq[rt] = *(const short8*)(ff + (size_t)(rowBase + rt * 16 + jj) * 32 + g * 8);

  f32x4 acc3[2][16];
#pragma unroll
  for (int rt = 0; rt < 2; ++rt)
#pragma unroll
    for (int c = 0; c < 16; ++c) acc3[rt][c] = z4;

  short8 w1c0 = w1f[lane], w1c1 = w1f[64 + lane];

  __syncthreads();  // slab0 staged

  // ---- GEMM2+3 over kt: h-slice in regs, W2 frags from LDS ----
  for (int t = 0; t < 16; ++t) {
    if (t < 15) STAGE_W2(t + 1, (t + 1) & 1);
    else STAGE_MP(0, 0);
    short8 w1n0 = w1c0, w1n1 = w1c1;
    if (t < 15) {
      w1n0 = w1f[(2 * t + 2) * 64 + lane];
      w1n1 = w1f[(2 * t + 3) * 64 + lane];
    }
    const char* buf = lds + (t & 1) * 16384;
    short8 hf[2];
#pragma unroll
    for (int half = 0; half < 2; ++half) {
      const int ct = 2 * t + half;
      f32x4 bb = *(const f32x4*)(b1 + ct * 16 + 4 * g);
      short8 a = half ? w1c1 : w1c0;
#pragma unroll
      for (int rt = 0; rt < 2; ++rt) {
        f32x4 d = MFMA(a, ffq[rt], z4);
#pragma unroll
        for (int i = 0; i < 4; ++i) {
          float v = d[i] + bb[i];
          v = v > 0.f ? v : 0.f;
          hf[rt][half * 4 + i] = bfb(v);
        }
      }
    }
#pragma unroll
    for (int c = 0; c < 16; ++c) {
      short8 bfr = *(const short8*)(buf + c * 1024 + lane * 16);
#pragma unroll
      for (int rt = 0; rt < 2; ++rt)
        acc3[rt][c] = MFMA(bfr, hf[rt], acc3[rt][c]);
    }
    w1c0 = w1n0;
    w1c1 = w1n1;
    __syncthreads();
  }

  // ---- q epilogue: bias, |q|^2, pack bf16 ----
  short8 qfrag[2][8];
  float invqn[2];
#pragma unroll
  for (int rt = 0; rt < 2; ++rt) {
    float qn = 0.f;
#pragma unroll
    for (int c = 0; c < 16; ++c) {
      f32x4 bb = *(const f32x4*)(b2 + c * 16 + 4 * g);
#pragma unroll
      for (int i = 0; i < 4; ++i) {
        float v = acc3[rt][c][i] + bb[i];
        qn += v * v;
        qfrag[rt][c >> 1][(c & 1) * 4 + i] = bfb(v);
      }
    }
    qn += __shfl_xor(qn, 16);
    qn += __shfl_xor(qn, 32);
    invqn[rt] = rsqrtf(fmaxf(qn, 1e-30f));
  }

  // ---- GEMM4: running max/argmax, Mp slabs from LDS ----
  float runmax[2][4];
  int runidx[2][4];
#pragma unroll
  for (int rt = 0; rt < 2; ++rt)
#pragma unroll
    for (int i = 0; i < 4; ++i) { runmax[rt][i] = -1e30f; runidx[rt][i] = 0; }

  for (int t = 0; t < 16; ++t) {
    if (t < 15) STAGE_MP(t + 1, (t + 1) & 1);
    const char* buf = lds + 32768 + (t & 1) * 32768;
    f32x4 a4[2][4];
#pragma unroll
    for (int rt = 0; rt < 2; ++rt)
#pragma unroll
      for (int nl = 0; nl < 4; ++nl) a4[rt][nl] = z4;
#pragma unroll
    for (int kt = 0; kt < 8; ++kt) {
#pragma unroll
      for (int nl = 0; nl < 4; ++nl) {
        short8 bfr = *(const short8*)(buf + (nl * 8 + kt) * 1024 + lane * 16);
#pragma unroll
        for (int rt = 0; rt < 2; ++rt)
          a4[rt][nl] = MFMA(qfrag[rt][kt], bfr, a4[rt][nl]);
      }
    }
#pragma unroll
    for (int nl = 0; nl < 4; ++nl) {
      int n = (t * 4 + nl) * 16 + jj;
#pragma unroll
      for (int rt = 0; rt < 2; ++rt)
#pragma unroll
        for (int i = 0; i < 4; ++i) {
          if (a4[rt][nl][i] > runmax[rt][i]) {
            runmax[rt][i] = a4[rt][nl][i];
            runidx[rt][i] = n;
          }
        }
    }
    __syncthreads();
  }

  // ---- reduce across jj-lanes (first-max tie-break), threshold, write ----
  const float4* mem4 = (const float4*)mem;
  float4* out4 = (float4*)out;
#pragma unroll
  for (int rt = 0; rt < 2; ++rt) {
#pragma unroll
    for (int i = 0; i < 4; ++i) {
#pragma unroll
      for (int o = 1; o < 16; o <<= 1) {
        float v2 = __shfl_xor(runmax[rt][i], o);
        int i2 = __shfl_xor(runidx[rt][i], o);
        if (v2 > runmax[rt][i] || (v2 == runmax[rt][i] && i2 < runidx[rt][i])) {
          runmax[rt][i] = v2;
          runidx[rt][i] = i2;
        }
      }
    }
#pragma unroll
    for (int i = 0; i < 4; ++i) {
      float iq = __shfl(invqn[rt], 4 * g + i, 64);  // lane (g'=0, jj=4g+i)
      float ms = runmax[rt][i] * iq;
      int s = (ms < 0.7f) ? -1 : runidx[rt][i];
      size_t row = (size_t)rowBase + rt * 16 + 4 * g + i;
#pragma unroll
      for (int cq = 0; cq < 4; ++cq) {
        int col = cq * 16 + jj;
        float4 v = {0.f, 0.f, 0.f, 0.f};
        if (s >= 0) v = mem4[(size_t)s * 64 + col];
        out4[row * 64 + col] = v;
      }
    }
  }
}

extern "C" void kernel_launch(void* const* d_in, const int* in_sizes, int n_in,
                              void* d_out, int out_size, void* d_ws, size_t ws_size,
                              hipStream_t stream) {
  const float* query = (const float*)d_in[0];
  const float* Bmat = (const float*)d_in[1];
  const float* W1 = (const float*)d_in[2];
  const float* b1 = (const float*)d_in[3];
  const float* W2 = (const float*)d_in[4];
  const float* b2 = (const float*)d_in[5];
  const float* mem = (const float*)d_in[6];
  float* out = (float*)d_out;

  char* ws = (char*)d_ws;
  __hip_bfloat16* ff = (__hip_bfloat16*)ws;                     // 4 MB
  __hip_bfloat16* Mp = (__hip_bfloat16*)(ws + 4194304);         // 512 KB
  __hip_bfloat16* W2p = (__hip_bfloat16*)(ws + 4194304 + 524288);  // 256 KB
  __hip_bfloat16* W1p = (__hip_bfloat16*)(ws + 4194304 + 786432);  // 32 KB

  prep_kernel<<<dim3(33), dim3(256), 0, stream>>>(W1, W2, mem, W1p, W2p, Mp);
  ff_kernel<<<dim3(4096), dim3(256), 0, stream>>>(query, Bmat, ff);
  mega_kernel<<<dim3(256), dim3(512), 0, stream>>>(ff, W1p, b1, W2p, b2, Mp, mem, out);
}

// Round 5
// 101.042 us; speedup vs baseline: 2.5638x; 1.1597x over previous
//
#include <hip/hip_runtime.h>
#include <hip/hip_bf16.h>

// ImmuneMemoryModule — MI355X pipeline v5.
// prep_ff (one kernel, role by blockIdx):
//   blocks 0..32:  pack W1/W2/memory into kappa-permuted lane-contiguous
//                  fragment layouts (bf16); memory rows pre-scaled 1/||m||.
//   blocks 33..:   ff = [sin,cos](query @ B_mat) -> [B][32] bf16 A-frag-ready;
//                  2 rows per 16-lane group (halves LDS broadcast per row).
// mega: 4 waves/block, 128 rows/block, grid 512 -> 2 blocks/CU. W2/Mp slabs
//   (16 KB) double-buffered via global_load_lds; the two co-resident blocks
//   have independent barriers, so one block computes while the other drains
//   its stage (fixes the 1-block/CU lockstep stall of v4). h/q stay in
//   registers via kappa slot-relabeling; 1/|q| folded into the final max.

typedef __attribute__((ext_vector_type(8))) short short8;
typedef __attribute__((ext_vector_type(4))) float f32x4;

#define MFMA(a, b, c) __builtin_amdgcn_mfma_f32_16x16x32_bf16((a), (b), (c), 0, 0, 0)

static __device__ __forceinline__ short bfb(float f) {
  return (short)__builtin_bit_cast(unsigned short, __float2bfloat16(f));
}
static __device__ __forceinline__ unsigned short bf16bits(float f) {
  return __builtin_bit_cast(unsigned short, __float2bfloat16(f));
}
static __device__ __forceinline__ float sel10(const float a[10], int i) {
  float v = a[0];
#pragma unroll
  for (int j = 1; j < 10; ++j) v = (i == j) ? a[j] : v;
  return v;
}

typedef const __attribute__((address_space(1))) unsigned int* gas_p;
typedef __attribute__((address_space(3))) unsigned int* las_p;
static __device__ __forceinline__ void async16(const void* g, void* l) {
  __builtin_amdgcn_global_load_lds((gas_p)g, (las_p)l, 16, 0, 0);
}

// ---------------------------------------------------------------------------
// prep_ff
// kappa(kt,g,j) = 32*kt + 16*(j>>2) + 4*g + (j&3)
// W1p [32 ct][64 lane][8 j]       = W1[8g+j][ct*16+jj]       (8g+j<20 else 0)
// W2p [16 kt][16 c][64 lane][8 j] = W2[kappa][c*16+jj]
// Mp  [16 cch][4 nl][8 kt][64 lane][8 j] = mhat[(cch*4+nl)*16+jj][kappa]
// ff  [B][32] bf16: k<10 sin(xp[k]), 10..19 cos(xp[k-10]), else 0
// ---------------------------------------------------------------------------
__global__ __launch_bounds__(256) void prep_ff_kernel(
    const float* __restrict__ W1, const float* __restrict__ W2,
    const float* __restrict__ mem, const float* __restrict__ query,
    const float* __restrict__ Bmat, __hip_bfloat16* __restrict__ W1p,
    __hip_bfloat16* __restrict__ W2p, __hip_bfloat16* __restrict__ Mp,
    __hip_bfloat16* __restrict__ ff) {
  __shared__ __align__(16) float Bl[10 * 512];  // ff: [f][d] 20KB; prep: invl
  const int b = blockIdx.x, tid = threadIdx.x;
  if (b < 16) {
    float* invl = Bl;  // [64]
    const int w = tid >> 6, lane = tid & 63, g = lane >> 4, jj = lane & 15;
    {
      int r = w * 16 + jj;  // 0..63 local row
      const float4* m4 = (const float4*)(mem + (size_t)(b * 64 + r) * 256);
      float ss = 0.f;
      for (int t = 0; t < 16; ++t) {
        float4 v = m4[g * 16 + t];
        ss += v.x * v.x + v.y * v.y + v.z * v.z + v.w * v.w;
      }
      ss += __shfl_xor(ss, 16);
      ss += __shfl_xor(ss, 32);
      if (g == 0) invl[r] = rsqrtf(fmaxf(ss, 1e-30f));
    }
    __syncthreads();
    for (int u = 0; u < 64; ++u) {
      int t = u * 256 + tid;  // 0..16383 within this chunk
      int j = t & 7, lane2 = (t >> 3) & 63, kt = (t >> 9) & 7, nl = t >> 12;
      int g2 = lane2 >> 4, jp = lane2 & 15;
      int nloc = nl * 16 + jp;
      int kap = 32 * kt + 16 * (j >> 2) + 4 * g2 + (j & 3);
      float v = mem[(size_t)(b * 64 + nloc) * 256 + kap] * invl[nloc];
      Mp[(size_t)b * 16384 + t] = __float2bfloat16(v);
    }
  } else if (b == 16) {
    for (int idx = tid; idx < 16384; idx += 256) {
      int j = idx & 7, lane2 = (idx >> 3) & 63, ct = idx >> 9;
      int g2 = lane2 >> 4, jp = lane2 & 15;
      int k = 8 * g2 + j;
      float v = (k < 20) ? W1[k * 512 + ct * 16 + jp] : 0.f;
      W1p[idx] = __float2bfloat16(v);
    }
  } else if (b < 33) {  // b = 17..32 -> W2p (131072 elems)
    int bb = b - 17;
    for (int u = 0; u < 32; ++u) {
      int idx = bb * 8192 + u * 256 + tid;
      int j = idx & 7, lane2 = (idx >> 3) & 63, c = (idx >> 9) & 15, kt = idx >> 13;
      int g2 = lane2 >> 4, jp = lane2 & 15;
      int kap = 32 * kt + 16 * (j >> 2) + 4 * g2 + (j & 3);
      W2p[idx] = __float2bfloat16(W2[(size_t)kap * 256 + c * 16 + jp]);
    }
  } else {
    // ---- ff: 32 rows/block, 2 rows per 16-lane group ----
    const int bb = b - 33;
    for (int i = tid; i < 5120; i += 256) {
      int d = i / 10, f = i - d * 10;
      Bl[f * 512 + d] = Bmat[i];  // B_mat row-major [512][10]
    }
    __syncthreads();
    const int wv = tid >> 6, lane = tid & 63;
    const int g = lane >> 4, jj = lane & 15;
    const long r0 = (long)bb * 32 + (wv * 4 + g) * 2;
    const float4* qa = (const float4*)(query + r0 * 512);
    const float4* qb = (const float4*)(query + (r0 + 1) * 512);

    float acc[2][10];
#pragma unroll
    for (int f = 0; f < 10; ++f) { acc[0][f] = 0.f; acc[1][f] = 0.f; }
#pragma unroll
    for (int k = 0; k < 8; ++k) {
      float4 va = qa[jj + 16 * k];
      float4 vb = qb[jj + 16 * k];
#pragma unroll
      for (int f = 0; f < 10; ++f) {
        float4 bv = *(const float4*)(Bl + f * 512 + 4 * (jj + 16 * k));
        acc[0][f] = fmaf(va.x, bv.x, fmaf(va.y, bv.y, fmaf(va.z, bv.z, fmaf(va.w, bv.w, acc[0][f]))));
        acc[1][f] = fmaf(vb.x, bv.x, fmaf(vb.y, bv.y, fmaf(vb.z, bv.z, fmaf(vb.w, bv.w, acc[1][f]))));
      }
    }
#pragma unroll
    for (int r = 0; r < 2; ++r) {
#pragma unroll
      for (int f = 0; f < 10; ++f) {
        float s = acc[r][f];
        s += __shfl_xor(s, 1); s += __shfl_xor(s, 2);
        s += __shfl_xor(s, 4); s += __shfl_xor(s, 8);
        acc[r][f] = s;
      }
      int base = (jj < 5) ? 2 * jj : 2 * jj - 10;
      float a0 = sel10(acc[r], base);
      float a1 = sel10(acc[r], base + 1);
      float v0 = 0.f, v1 = 0.f;
      if (jj < 5) { v0 = sinf(a0); v1 = sinf(a1); }
      else if (jj < 10) { v0 = cosf(a0); v1 = cosf(a1); }
      ushort2 pk;
      pk.x = bf16bits(v0);
      pk.y = bf16bits(v1);
      ((ushort2*)ff)[(r0 + r) * 16 + jj] = pk;
    }
  }
}

// ---------------------------------------------------------------------------
// mega: 256 threads (4 waves), 32 rows/wave, grid 512 -> 2 blocks/CU.
// LDS 64KB: [0,32K) W2 dbuf (2x16K), [32K,64K) Mp dbuf (2x16K).
// ---------------------------------------------------------------------------
#define STAGE_W2(slab, bufi)                                      \
  do {                                                            \
    const char* s_ = (const char*)W2p + (slab)*16384 + tid * 16;  \
    char* d_ = lds + (bufi)*16384 + tid * 16;                     \
    async16(s_, d_);                                              \
    async16(s_ + 4096, d_ + 4096);                                \
    async16(s_ + 8192, d_ + 8192);                                \
    async16(s_ + 12288, d_ + 12288);                              \
  } while (0)

#define STAGE_MP(slab, bufi)                                      \
  do {                                                            \
    const char* s_ = (const char*)Mp + (slab)*16384 + tid * 16;   \
    char* d_ = lds + 32768 + (bufi)*16384 + tid * 16;             \
    async16(s_, d_);                                              \
    async16(s_ + 4096, d_ + 4096);                                \
    async16(s_ + 8192, d_ + 8192);                                \
    async16(s_ + 12288, d_ + 12288);                              \
  } while (0)

__global__ __launch_bounds__(256, 2) void mega_kernel(
    const __hip_bfloat16* __restrict__ ff, const __hip_bfloat16* __restrict__ W1p,
    const float* __restrict__ b1, const __hip_bfloat16* __restrict__ W2p,
    const float* __restrict__ b2, const __hip_bfloat16* __restrict__ Mp,
    const float* __restrict__ mem, float* __restrict__ out) {
  __shared__ __align__(16) char lds[65536];
  const int tid = threadIdx.x, w = tid >> 6, lane = tid & 63;
  const int g = lane >> 4, jj = lane & 15;
  const int rowBase = blockIdx.x * 128 + w * 32;
  const f32x4 z4 = {0.f, 0.f, 0.f, 0.f};
  const short8* w1f = (const short8*)W1p;

  STAGE_W2(0, 0);

  // ff A-frags (linear layout: slot (g,j) = ff[row][8g+j])
  short8 ffq[2];
#pragma unroll
  for (int rt = 0; rt < 2; ++rt)
    ffq[rt] = *(const short8*)(ff + (size_t)(rowBase + rt * 16 + jj) * 32 + g * 8);

  f32x4 acc3[2][16];
#pragma unroll
  for (int rt = 0; rt < 2; ++rt)
#pragma unroll
    for (int c = 0; c < 16; ++c) acc3[rt][c] = z4;

  short8 w1c0 = w1f[lane], w1c1 = w1f[64 + lane];

  __syncthreads();  // slab0 staged

  // ---- GEMM2+3 over kt: h-slice in regs, W2 frags from LDS ----
  for (int t = 0; t < 16; ++t) {
    if (t < 15) STAGE_W2(t + 1, (t + 1) & 1);
    else STAGE_MP(0, 0);
    short8 w1n0 = w1c0, w1n1 = w1c1;
    if (t < 15) {
      w1n0 = w1f[(2 * t + 2) * 64 + lane];
      w1n1 = w1f[(2 * t + 3) * 64 + lane];
    }
    const char* buf = lds + (t & 1) * 16384;
    short8 hf[2];
#pragma unroll
    for (int half = 0; half < 2; ++half) {
      const int ct = 2 * t + half;
      f32x4 bb = *(const f32x4*)(b1 + ct * 16 + 4 * g);
      short8 a = half ? w1c1 : w1c0;
#pragma unroll
      for (int rt = 0; rt < 2; ++rt) {
        f32x4 d = MFMA(a, ffq[rt], z4);
#pragma unroll
        for (int i = 0; i < 4; ++i) {
          float v = d[i] + bb[i];
          v = v > 0.f ? v : 0.f;
          hf[rt][half * 4 + i] = bfb(v);
        }
      }
    }
#pragma unroll
    for (int c = 0; c < 16; ++c) {
      short8 bfr = *(const short8*)(buf + c * 1024 + lane * 16);
#pragma unroll
      for (int rt = 0; rt < 2; ++rt)
        acc3[rt][c] = MFMA(bfr, hf[rt], acc3[rt][c]);
    }
    w1c0 = w1n0;
    w1c1 = w1n1;
    __syncthreads();
  }

  // ---- q epilogue: bias, |q|^2, pack bf16 ----
  short8 qfrag[2][8];
  float invqn[2];
#pragma unroll
  for (int rt = 0; rt < 2; ++rt) {
    float qn = 0.f;
#pragma unroll
    for (int c = 0; c < 16; ++c) {
      f32x4 bb = *(const f32x4*)(b2 + c * 16 + 4 * g);
#pragma unroll
      for (int i = 0; i < 4; ++i) {
        float v = acc3[rt][c][i] + bb[i];
        qn += v * v;
        qfrag[rt][c >> 1][(c & 1) * 4 + i] = bfb(v);
      }
    }
    qn += __shfl_xor(qn, 16);
    qn += __shfl_xor(qn, 32);
    invqn[rt] = rsqrtf(fmaxf(qn, 1e-30f));
  }

  // ---- GEMM4: running max/argmax, Mp slabs (16KB = 2 n-groups) from LDS ----
  float runmax[2][4];
  int runidx[2][4];
#pragma unroll
  for (int rt = 0; rt < 2; ++rt)
#pragma unroll
    for (int i = 0; i < 4; ++i) { runmax[rt][i] = -1e30f; runidx[rt][i] = 0; }

  for (int t = 0; t < 32; ++t) {
    if (t < 31) STAGE_MP(t + 1, (t + 1) & 1);
    const char* buf = lds + 32768 + (t & 1) * 16384;
    f32x4 a4[2][2];
#pragma unroll
    for (int rt = 0; rt < 2; ++rt)
#pragma unroll
      for (int nl = 0; nl < 2; ++nl) a4[rt][nl] = z4;
#pragma unroll
    for (int kt = 0; kt < 8; ++kt) {
#pragma unroll
      for (int nl = 0; nl < 2; ++nl) {
        short8 bfr = *(const short8*)(buf + (nl * 8 + kt) * 1024 + lane * 16);
#pragma unroll
        for (int rt = 0; rt < 2; ++rt)
          a4[rt][nl] = MFMA(qfrag[rt][kt], bfr, a4[rt][nl]);
      }
    }
#pragma unroll
    for (int nl = 0; nl < 2; ++nl) {
      int n = (t * 2 + nl) * 16 + jj;
#pragma unroll
      for (int rt = 0; rt < 2; ++rt)
#pragma unroll
        for (int i = 0; i < 4; ++i) {
          if (a4[rt][nl][i] > runmax[rt][i]) {
            runmax[rt][i] = a4[rt][nl][i];
            runidx[rt][i] = n;
          }
        }
    }
    __syncthreads();
  }

  // ---- reduce across jj-lanes (first-max tie-break), threshold, write ----
  const float4* mem4 = (const float4*)mem;
  float4* out4 = (float4*)out;
#pragma unroll
  for (int rt = 0; rt < 2; ++rt) {
#pragma unroll
    for (int i = 0; i < 4; ++i) {
#pragma unroll
      for (int o = 1; o < 16; o <<= 1) {
        float v2 = __shfl_xor(runmax[rt][i], o);
        int i2 = __shfl_xor(runidx[rt][i], o);
        if (v2 > runmax[rt][i] || (v2 == runmax[rt][i] && i2 < runidx[rt][i])) {
          runmax[rt][i] = v2;
          runidx[rt][i] = i2;
        }
      }
    }
#pragma unroll
    for (int i = 0; i < 4; ++i) {
      float iq = __shfl(invqn[rt], 4 * g + i, 64);  // lane (g'=0, jj=4g+i)
      float ms = runmax[rt][i] * iq;
      int s = (ms < 0.7f) ? -1 : runidx[rt][i];
      size_t row = (size_t)rowBase + rt * 16 + 4 * g + i;
#pragma unroll
      for (int cq = 0; cq < 4; ++cq) {
        int col = cq * 16 + jj;
        float4 v = {0.f, 0.f, 0.f, 0.f};
        if (s >= 0) v = mem4[(size_t)s * 64 + col];
        out4[row * 64 + col] = v;
      }
    }
  }
}

extern "C" void kernel_launch(void* const* d_in, const int* in_sizes, int n_in,
                              void* d_out, int out_size, void* d_ws, size_t ws_size,
                              hipStream_t stream) {
  const float* query = (const float*)d_in[0];
  const float* Bmat = (const float*)d_in[1];
  const float* W1 = (const float*)d_in[2];
  const float* b1 = (const float*)d_in[3];
  const float* W2 = (const float*)d_in[4];
  const float* b2 = (const float*)d_in[5];
  const float* mem = (const float*)d_in[6];
  float* out = (float*)d_out;

  char* ws = (char*)d_ws;
  __hip_bfloat16* ff = (__hip_bfloat16*)ws;                        // 4 MB
  __hip_bfloat16* Mp = (__hip_bfloat16*)(ws + 4194304);            // 512 KB
  __hip_bfloat16* W2p = (__hip_bfloat16*)(ws + 4194304 + 524288);  // 256 KB
  __hip_bfloat16* W1p = (__hip_bfloat16*)(ws + 4194304 + 786432);  // 32 KB

  prep_ff_kernel<<<dim3(2081), dim3(256), 0, stream>>>(W1, W2, mem, query, Bmat,
                                                       W1p, W2p, Mp, ff);
  mega_kernel<<<dim3(512), dim3(256), 0, stream>>>(ff, W1p, b1, W2p, b2, Mp, mem, out);
}